// Round 1
// baseline (414.279 us; speedup 1.0000x reference)
//
#include <hip/hip_runtime.h>
#include <hip/hip_bf16.h>

#define H 16
#define DKH 64
#define BB 2
#define SS 2048
#define DMODEL 1024
#define ROWS (BB * SS)   // 4096

typedef __attribute__((ext_vector_type(8))) short bf16x8;
typedef __attribute__((ext_vector_type(4))) float f32x4;
typedef __attribute__((ext_vector_type(4))) float float4v;

__device__ __forceinline__ short f2bf(float f) {
    union { float f; unsigned u; } v; v.f = f;
    unsigned r = v.u + 0x7fffu + ((v.u >> 16) & 1u);
    return (short)(r >> 16);
}

// C[M][N] = A[M][K] * B[N][K]^T + bias, K = 1024.
// OUT_MODE: 0 = fp32 row-major, 1 = bf16 row-major, 2 = bf16 head-major [B,H,S,64]
// A_BF16:   A operand is bf16 (else fp32, converted during staging)
// BIAS_ROW: bias indexed by m (row) instead of n (col)
template<int OUT_MODE, int A_BF16, int BIAS_ROW>
__global__ __launch_bounds__(256, 2)
void gemm_bt(const void* __restrict__ Aptr, const float* __restrict__ Bptr,
             const float* __restrict__ bias, void* __restrict__ Cptr,
             int M, int N, float scale)
{
    const int K = DMODEL;
    __shared__ short As[128][40];   // 128x32 tile, stride 40 (16B-aligned rows, low bank aliasing)
    __shared__ short Bs[64][40];

    const int t    = threadIdx.x;
    const int lane = t & 63;
    const int wid  = t >> 6;
    const int wm   = wid >> 1;      // 0..1
    const int wn   = wid & 1;       // 0..1
    const int m0   = blockIdx.y * 128;
    const int n0   = blockIdx.x * 64;
    const int l15  = lane & 15;
    const int l4   = lane >> 4;

    f32x4 acc[4][2];
#pragma unroll
    for (int i = 0; i < 4; i++)
#pragma unroll
        for (int j = 0; j < 2; j++) acc[i][j] = (f32x4)0.0f;

    const int arow = t >> 1;         // 0..127
    const int akc  = (t & 1) * 16;   // 0 / 16
    const int brow = t >> 2;         // 0..63
    const int bkc  = (t & 3) * 8;    // 0..24

    for (int kt = 0; kt < K; kt += 32) {
        // ---- stage A tile (128x32) ----
        if constexpr (A_BF16) {
            const short* A = (const short*)Aptr;
            const bf16x8* src = (const bf16x8*)&A[(size_t)(m0 + arow) * K + kt + akc];
            bf16x8 v0 = src[0], v1 = src[1];
            *(bf16x8*)&As[arow][akc]     = v0;
            *(bf16x8*)&As[arow][akc + 8] = v1;
        } else {
            const float* A = (const float*)Aptr;
            const float4v* src = (const float4v*)&A[(size_t)(m0 + arow) * K + kt + akc];
            float4v f0 = src[0], f1 = src[1], f2 = src[2], f3 = src[3];
            bf16x8 v0, v1;
            v0[0]=f2bf(f0[0]); v0[1]=f2bf(f0[1]); v0[2]=f2bf(f0[2]); v0[3]=f2bf(f0[3]);
            v0[4]=f2bf(f1[0]); v0[5]=f2bf(f1[1]); v0[6]=f2bf(f1[2]); v0[7]=f2bf(f1[3]);
            v1[0]=f2bf(f2[0]); v1[1]=f2bf(f2[1]); v1[2]=f2bf(f2[2]); v1[3]=f2bf(f2[3]);
            v1[4]=f2bf(f3[0]); v1[5]=f2bf(f3[1]); v1[6]=f2bf(f3[2]); v1[7]=f2bf(f3[3]);
            *(bf16x8*)&As[arow][akc]     = v0;
            *(bf16x8*)&As[arow][akc + 8] = v1;
        }
        // ---- stage B tile (64x32), always fp32 source ----
        {
            const float4v* src = (const float4v*)&Bptr[(size_t)(n0 + brow) * K + kt + bkc];
            float4v g0 = src[0], g1 = src[1];
            bf16x8 w;
            w[0]=f2bf(g0[0]); w[1]=f2bf(g0[1]); w[2]=f2bf(g0[2]); w[3]=f2bf(g0[3]);
            w[4]=f2bf(g1[0]); w[5]=f2bf(g1[1]); w[6]=f2bf(g1[2]); w[7]=f2bf(g1[3]);
            *(bf16x8*)&Bs[brow][bkc] = w;
        }
        __syncthreads();

        bf16x8 a[4], b[2];
#pragma unroll
        for (int i = 0; i < 4; i++)
            a[i] = *(const bf16x8*)&As[wm * 64 + i * 16 + l15][l4 * 8];
#pragma unroll
        for (int j = 0; j < 2; j++)
            b[j] = *(const bf16x8*)&Bs[wn * 32 + j * 16 + l15][l4 * 8];
#pragma unroll
        for (int i = 0; i < 4; i++)
#pragma unroll
            for (int j = 0; j < 2; j++)
                acc[i][j] = __builtin_amdgcn_mfma_f32_16x16x32_bf16(a[i], b[j], acc[i][j], 0, 0, 0);

        __syncthreads();
    }

    // ---- epilogue ----
#pragma unroll
    for (int i = 0; i < 4; i++) {
        const int mbase = m0 + wm * 64 + i * 16 + l4 * 4;
#pragma unroll
        for (int j = 0; j < 2; j++) {
            const int n = n0 + wn * 32 + j * 16 + l15;
#pragma unroll
            for (int r = 0; r < 4; r++) {
                const int m = mbase + r;
                float y = acc[i][j][r] + (BIAS_ROW ? bias[m] : bias[n]);
                y *= scale;
                if constexpr (OUT_MODE == 0) {
                    ((float*)Cptr)[(size_t)m * N + n] = y;
                } else if constexpr (OUT_MODE == 1) {
                    ((short*)Cptr)[(size_t)m * N + n] = f2bf(y);
                } else {
                    const int b_ = m >> 11, s_ = m & 2047;
                    const int h_ = n >> 6,  d_ = n & 63;
                    ((short*)Cptr)[((((size_t)b_ * H + h_) * SS + s_) << 6) + d_] = f2bf(y);
                }
            }
        }
    }
}

// Flash attention, causal. Grid (S/64, B*H), 256 threads (4 waves x 16 q-rows).
// Qh/Kh: bf16 [B,H,S,64]; Vt: bf16 [e=h*64+d][b*S+s]; Oc: bf16 [B*S][1024].
__global__ __launch_bounds__(256, 2)
void attn_fwd(const short* __restrict__ Qh, const short* __restrict__ Kh,
              const short* __restrict__ Vt, short* __restrict__ Oc)
{
    __shared__ short Ks[64][72];
    __shared__ short Vs[64][72];     // Vs[d][kv]
    __shared__ short Ps[4][16][72];  // per-wave P tile

    const int t    = threadIdx.x;
    const int lane = t & 63;
    const int wid  = t >> 6;
    const int qt   = blockIdx.x;
    const int bh   = blockIdx.y;     // b*H + h
    const int b    = bh >> 4;
    const int h    = bh & 15;
    const int l15  = lane & 15;
    const int l4   = lane >> 4;

    // Q fragments (held in registers for the whole block)
    bf16x8 qa[2];
    {
        const int qrow = qt * 64 + wid * 16 + l15;
        const size_t base = ((size_t)bh * SS + qrow) * 64;
        qa[0] = *(const bf16x8*)&Qh[base + l4 * 8];
        qa[1] = *(const bf16x8*)&Qh[base + 32 + l4 * 8];
    }

    f32x4 accO[4];
#pragma unroll
    for (int i = 0; i < 4; i++) accO[i] = (f32x4)0.f;
    float mrun[4], lrun[4];
#pragma unroll
    for (int r = 0; r < 4; r++) { mrun[r] = -1e30f; lrun[r] = 0.f; }

    const int srow = t >> 2;        // 0..63
    const int skc  = (t & 3) * 16;  // 0,16,32,48

    for (int kvt = 0; kvt <= qt; ++kvt) {
        {   // stage K tile [kv][dk]
            const bf16x8* src = (const bf16x8*)&Kh[((size_t)bh * SS + kvt * 64 + srow) * 64 + skc];
            bf16x8 v0 = src[0], v1 = src[1];
            *(bf16x8*)&Ks[srow][skc]     = v0;
            *(bf16x8*)&Ks[srow][skc + 8] = v1;
        }
        {   // stage Vt tile [d][kv]
            const bf16x8* src = (const bf16x8*)&Vt[((size_t)(h * 64 + srow)) * ROWS + b * SS + kvt * 64 + skc];
            bf16x8 v0 = src[0], v1 = src[1];
            *(bf16x8*)&Vs[srow][skc]     = v0;
            *(bf16x8*)&Vs[srow][skc + 8] = v1;
        }
        __syncthreads();

        // S = Q K^T (pre-scaled by 1/8 via Q)
        f32x4 sc[4];
#pragma unroll
        for (int i = 0; i < 4; i++) sc[i] = (f32x4)0.f;
#pragma unroll
        for (int kk = 0; kk < 2; kk++) {
#pragma unroll
            for (int fn = 0; fn < 4; fn++) {
                bf16x8 kb = *(const bf16x8*)&Ks[fn * 16 + l15][kk * 32 + l4 * 8];
                sc[fn] = __builtin_amdgcn_mfma_f32_16x16x32_bf16(qa[kk], kb, sc[fn], 0, 0, 0);
            }
        }

        if (kvt == qt) {   // causal mask inside diagonal tile
#pragma unroll
            for (int fn = 0; fn < 4; fn++) {
                const int kvg = fn * 16 + l15;
#pragma unroll
                for (int r = 0; r < 4; r++) {
                    const int qg = wid * 16 + l4 * 4 + r;
                    if (kvg > qg) sc[fn][r] = -1e30f;
                }
            }
        }

        // online softmax (rows live across 16-lane groups, one row per reg)
        float es[4], rs[4];
#pragma unroll
        for (int r = 0; r < 4; r++) {
            float v = fmaxf(fmaxf(sc[0][r], sc[1][r]), fmaxf(sc[2][r], sc[3][r]));
            v = fmaxf(v, __shfl_xor(v, 1));
            v = fmaxf(v, __shfl_xor(v, 2));
            v = fmaxf(v, __shfl_xor(v, 4));
            v = fmaxf(v, __shfl_xor(v, 8));
            const float mn = fmaxf(mrun[r], v);
            es[r] = __expf(mrun[r] - mn);
            mrun[r] = mn;
            rs[r] = 0.f;
        }
#pragma unroll
        for (int fn = 0; fn < 4; fn++)
#pragma unroll
            for (int r = 0; r < 4; r++) {
                const float p = __expf(sc[fn][r] - mrun[r]);
                sc[fn][r] = p;
                rs[r] += p;
            }
#pragma unroll
        for (int r = 0; r < 4; r++) {
            float v = rs[r];
            v += __shfl_xor(v, 1);
            v += __shfl_xor(v, 2);
            v += __shfl_xor(v, 4);
            v += __shfl_xor(v, 8);
            lrun[r] = lrun[r] * es[r] + v;
        }
#pragma unroll
        for (int i = 0; i < 4; i++)
#pragma unroll
            for (int r = 0; r < 4; r++) accO[i][r] *= es[r];

        // P -> per-wave LDS (C-layout -> A-fragment layout)
#pragma unroll
        for (int fn = 0; fn < 4; fn++)
#pragma unroll
            for (int r = 0; r < 4; r++)
                Ps[wid][l4 * 4 + r][fn * 16 + l15] = f2bf(sc[fn][r]);

        // O += P V   (B-operand = Vt rows: contiguous kv)
#pragma unroll
        for (int kk = 0; kk < 2; kk++) {
            bf16x8 pa = *(const bf16x8*)&Ps[wid][l15][kk * 32 + l4 * 8];
#pragma unroll
            for (int fd = 0; fd < 4; fd++) {
                bf16x8 vb = *(const bf16x8*)&Vs[fd * 16 + l15][kk * 32 + l4 * 8];
                accO[fd] = __builtin_amdgcn_mfma_f32_16x16x32_bf16(pa, vb, accO[fd], 0, 0, 0);
            }
        }

        __syncthreads();
    }

    // epilogue: normalize, store concat-heads bf16 [B*S][1024]
    float inv[4];
#pragma unroll
    for (int r = 0; r < 4; r++) inv[r] = 1.0f / lrun[r];
#pragma unroll
    for (int fd = 0; fd < 4; fd++)
#pragma unroll
        for (int r = 0; r < 4; r++) {
            const int q = qt * 64 + wid * 16 + l4 * 4 + r;
            const size_t idx = ((size_t)b * SS + q) * DMODEL + h * 64 + fd * 16 + l15;
            Oc[idx] = f2bf(accO[fd][r] * inv[r]);
        }
}

extern "C" void kernel_launch(void* const* d_in, const int* in_sizes, int n_in,
                              void* d_out, int out_size, void* d_ws, size_t ws_size,
                              hipStream_t stream) {
    const float* q   = (const float*)d_in[0];
    const float* k   = (const float*)d_in[1];
    const float* v   = (const float*)d_in[2];
    // d_in[3] = causal mask (tril) -- enforced analytically, not read
    const float* w_q = (const float*)d_in[4];
    const float* b_q = (const float*)d_in[5];
    const float* w_k = (const float*)d_in[6];
    const float* b_k = (const float*)d_in[7];
    const float* w_v = (const float*)d_in[8];
    const float* b_v = (const float*)d_in[9];
    const float* w_o = (const float*)d_in[10];
    const float* b_o = (const float*)d_in[11];

    short* Qh = (short*)d_ws;                       // [B,H,S,64] bf16
    short* Kh = Qh + (size_t)ROWS * DMODEL;         // [B,H,S,64] bf16
    short* Vt = Kh + (size_t)ROWS * DMODEL;         // [1024][4096] bf16 (V transposed)
    short* Oc = Vt + (size_t)ROWS * DMODEL;         // [4096][1024] bf16

    dim3 blk(256);
    // Q projection (scaled by 1/sqrt(64)), head-major out
    gemm_bt<2, 0, 0><<<dim3(16, 32), blk, 0, stream>>>(q, w_q, b_q, Qh, ROWS, DMODEL, 0.125f);
    // K projection, head-major out
    gemm_bt<2, 0, 0><<<dim3(16, 32), blk, 0, stream>>>(k, w_k, b_k, Kh, ROWS, DMODEL, 1.0f);
    // V projection computed transposed: Vt[e][bs] = sum_d w_v[e][d] * v[bs][d] + b_v[e]
    gemm_bt<1, 0, 1><<<dim3(64, 8), blk, 0, stream>>>(w_v, v, b_v, Vt, DMODEL, ROWS, 1.0f);
    // attention
    attn_fwd<<<dim3(32, 32), blk, 0, stream>>>(Qh, Kh, Vt, Oc);
    // output projection, fp32 out
    gemm_bt<0, 1, 0><<<dim3(16, 32), blk, 0, stream>>>(Oc, w_o, b_o, (float*)d_out, ROWS, DMODEL, 1.0f);
}

// Round 2
// 371.464 us; speedup vs baseline: 1.1153x; 1.1153x over previous
//
#include <hip/hip_runtime.h>
#include <hip/hip_bf16.h>

#define H 16
#define BB 2
#define SS 2048
#define DMODEL 1024
#define ROWS (BB * SS)   // 4096
#define QTILES (SS / 64) // 32

typedef __attribute__((ext_vector_type(8))) short bf16x8;
typedef __attribute__((ext_vector_type(4))) float f32x4;

__device__ __forceinline__ short f2bf(float f) {
    union { float f; unsigned u; } v; v.f = f;
    unsigned r = v.u + 0x7fffu + ((v.u >> 16) & 1u);
    return (short)(r >> 16);
}

__device__ __forceinline__ void gload_lds16(const void* g, void* l) {
    __builtin_amdgcn_global_load_lds(
        (const __attribute__((address_space(1))) char*)g,
        (__attribute__((address_space(3))) char*)l, 16, 0, 0);
}

// fp32 -> bf16 convert for q,k,v. grid (1024, 3), 256 thr. 4M elems per tensor.
__global__ __launch_bounds__(256)
void cvt3(const float* __restrict__ q, const float* __restrict__ k,
          const float* __restrict__ v, short* __restrict__ dq,
          short* __restrict__ dk, short* __restrict__ dv)
{
    const float* s = (blockIdx.y == 0) ? q : (blockIdx.y == 1) ? k : v;
    short*       d = (blockIdx.y == 0) ? dq : (blockIdx.y == 1) ? dk : dv;
    const f32x4* sv = (const f32x4*)s;
    bf16x8* dv8 = (bf16x8*)d;
    int p = blockIdx.x * 256 + threadIdx.x;   // bf16x8 index
#pragma unroll
    for (int it = 0; it < 2; ++it, p += 1024 * 256) {
        f32x4 a = sv[2 * p], c = sv[2 * p + 1];
        bf16x8 o;
        o[0] = f2bf(a[0]); o[1] = f2bf(a[1]); o[2] = f2bf(a[2]); o[3] = f2bf(a[3]);
        o[4] = f2bf(c[0]); o[5] = f2bf(c[1]); o[6] = f2bf(c[2]); o[7] = f2bf(c[3]);
        dv8[p] = o;
    }
}

// C[M][N] = A[M][K] * B[N][K]^T + bias, K=1024. 128x128 tile, BK=32, 4 waves.
// OUT_MODE: 0 fp32 row-major, 1 bf16 row-major, 2 bf16 head-major [B,H,S,64]
// A_BF16/B_BF16: operand already bf16 (global_load_lds) else fp32 (reg-convert)
template<int OUT_MODE, int A_BF16, int B_BF16, int BIAS_ROW>
__global__ __launch_bounds__(256, 2)
void gemm_bt(const void* __restrict__ Aptr, const void* __restrict__ Bptr,
             const float* __restrict__ bias, void* __restrict__ Cptr,
             int M, int N, float scale)
{
    const int K = DMODEL;
    __shared__ short As[128][32];
    __shared__ short Bs[128][32];

    const int t    = threadIdx.x;
    const int lane = t & 63;
    const int wid  = t >> 6;
    const int wm   = wid >> 1;
    const int wn   = wid & 1;
    const int m0   = blockIdx.y * 128;
    const int n0   = blockIdx.x * 128;
    const int l15  = lane & 15;
    const int l4   = lane >> 4;

    f32x4 acc[4][4];
#pragma unroll
    for (int i = 0; i < 4; i++)
#pragma unroll
        for (int j = 0; j < 4; j++) acc[i][j] = (f32x4)0.0f;

    // bf16 staging geometry (global_load_lds, linear LDS)
    const int grow = wid * 16 + (lane >> 2);   // + i*64
    const int gcol = (lane & 3) * 8;           // shorts
    // fp32 staging geometry (reg convert)
    const int frow = t >> 1;                   // 0..127
    const int fcol = (t & 1) * 16;             // floats

    for (int kt = 0; kt < K; kt += 32) {
        if constexpr (A_BF16) {
            const short* A = (const short*)Aptr;
#pragma unroll
            for (int i = 0; i < 2; i++)
                gload_lds16(&A[(size_t)(m0 + i * 64 + grow) * K + kt + gcol],
                            (char*)As + wid * 1024 + i * 4096);
        } else {
            const float* A = (const float*)Aptr;
            const f32x4* src = (const f32x4*)&A[(size_t)(m0 + frow) * K + kt + fcol];
            f32x4 f0 = src[0], f1 = src[1], f2 = src[2], f3 = src[3];
            bf16x8 v0, v1;
            v0[0]=f2bf(f0[0]); v0[1]=f2bf(f0[1]); v0[2]=f2bf(f0[2]); v0[3]=f2bf(f0[3]);
            v0[4]=f2bf(f1[0]); v0[5]=f2bf(f1[1]); v0[6]=f2bf(f1[2]); v0[7]=f2bf(f1[3]);
            v1[0]=f2bf(f2[0]); v1[1]=f2bf(f2[1]); v1[2]=f2bf(f2[2]); v1[3]=f2bf(f2[3]);
            v1[4]=f2bf(f3[0]); v1[5]=f2bf(f3[1]); v1[6]=f2bf(f3[2]); v1[7]=f2bf(f3[3]);
            *(bf16x8*)&As[frow][fcol]     = v0;
            *(bf16x8*)&As[frow][fcol + 8] = v1;
        }
        if constexpr (B_BF16) {
            const short* B = (const short*)Bptr;
#pragma unroll
            for (int i = 0; i < 2; i++)
                gload_lds16(&B[(size_t)(n0 + i * 64 + grow) * K + kt + gcol],
                            (char*)Bs + wid * 1024 + i * 4096);
        } else {
            const float* B = (const float*)Bptr;
            const f32x4* src = (const f32x4*)&B[(size_t)(n0 + frow) * K + kt + fcol];
            f32x4 f0 = src[0], f1 = src[1], f2 = src[2], f3 = src[3];
            bf16x8 v0, v1;
            v0[0]=f2bf(f0[0]); v0[1]=f2bf(f0[1]); v0[2]=f2bf(f0[2]); v0[3]=f2bf(f0[3]);
            v0[4]=f2bf(f1[0]); v0[5]=f2bf(f1[1]); v0[6]=f2bf(f1[2]); v0[7]=f2bf(f1[3]);
            v1[0]=f2bf(f2[0]); v1[1]=f2bf(f2[1]); v1[2]=f2bf(f2[2]); v1[3]=f2bf(f2[3]);
            v1[4]=f2bf(f3[0]); v1[5]=f2bf(f3[1]); v1[6]=f2bf(f3[2]); v1[7]=f2bf(f3[3]);
            *(bf16x8*)&Bs[frow][fcol]     = v0;
            *(bf16x8*)&Bs[frow][fcol + 8] = v1;
        }
        __syncthreads();

        bf16x8 a[4], b[4];
#pragma unroll
        for (int i = 0; i < 4; i++)
            a[i] = *(const bf16x8*)&As[wm * 64 + i * 16 + l15][l4 * 8];
#pragma unroll
        for (int j = 0; j < 4; j++)
            b[j] = *(const bf16x8*)&Bs[wn * 64 + j * 16 + l15][l4 * 8];
#pragma unroll
        for (int i = 0; i < 4; i++)
#pragma unroll
            for (int j = 0; j < 4; j++)
                acc[i][j] = __builtin_amdgcn_mfma_f32_16x16x32_bf16(a[i], b[j], acc[i][j], 0, 0, 0);

        __syncthreads();
    }

#pragma unroll
    for (int i = 0; i < 4; i++) {
        const int mbase = m0 + wm * 64 + i * 16 + l4 * 4;
#pragma unroll
        for (int j = 0; j < 4; j++) {
            const int n = n0 + wn * 64 + j * 16 + l15;
#pragma unroll
            for (int r = 0; r < 4; r++) {
                const int m = mbase + r;
                float y = acc[i][j][r] + (BIAS_ROW ? bias[m] : bias[n]);
                y *= scale;
                if constexpr (OUT_MODE == 0) {
                    ((float*)Cptr)[(size_t)m * N + n] = y;
                } else if constexpr (OUT_MODE == 1) {
                    ((short*)Cptr)[(size_t)m * N + n] = f2bf(y);
                } else {
                    const int b_ = m >> 11, s_ = m & 2047;
                    const int h_ = n >> 6,  d_ = n & 63;
                    ((short*)Cptr)[((((size_t)b_ * H + h_) * SS + s_) << 6) + d_] = f2bf(y);
                }
            }
        }
    }
}

// Flash attention, causal, paired q-tiles for balance.
// Grid (16, B*H), 256 thr. Block bx does qt=bx then qt=31-bx (33 kv-iters total).
__global__ __launch_bounds__(256, 2)
void attn_fwd(const short* __restrict__ Qh, const short* __restrict__ Kh,
              const short* __restrict__ Vt, short* __restrict__ Oc)
{
    __shared__ short Ks[64][64];     // [kv][dk], XOR-swizzled chunks
    __shared__ short Vs[64][64];     // [d][kv],  XOR-swizzled chunks
    __shared__ short Ps[4][16][72];  // per-wave P tile

    const int t    = threadIdx.x;
    const int lane = t & 63;
    const int wid  = t >> 6;
    const int bh   = blockIdx.y;
    const int b    = bh >> 4;
    const int h    = bh & 15;
    const int l15  = lane & 15;
    const int l4   = lane >> 4;

    // staging geometry: 2 instrs/thread per 8KB tile; swizzled source chunk
    const int srow = wid * 8 + (lane >> 3);          // + i*32, row 0..63
    const int sch  = lane & 7;                       // chunk in LDS
    const int ldsoff = wid * 1024;                   // + i*4096, bytes

    for (int half = 0; half < 2; ++half) {
        const int qt = half ? (31 - (int)blockIdx.x) : (int)blockIdx.x;

        bf16x8 qa[2];
        {
            const int qrow = qt * 64 + wid * 16 + l15;
            const size_t base = ((size_t)bh * SS + qrow) * 64;
            qa[0] = *(const bf16x8*)&Qh[base + l4 * 8];
            qa[1] = *(const bf16x8*)&Qh[base + 32 + l4 * 8];
        }

        f32x4 accO[4];
#pragma unroll
        for (int i = 0; i < 4; i++) accO[i] = (f32x4)0.f;
        float mrun[4], lrun[4];
#pragma unroll
        for (int r = 0; r < 4; r++) { mrun[r] = -1e30f; lrun[r] = 0.f; }

        for (int kvt = 0; kvt <= qt; ++kvt) {
#pragma unroll
            for (int i = 0; i < 2; i++) {
                const int row = i * 32 + srow;
                const int chg = sch ^ (row & 7);
                gload_lds16(&Kh[((size_t)bh * SS + kvt * 64 + row) * 64 + chg * 8],
                            (char*)Ks + ldsoff + i * 4096);
                gload_lds16(&Vt[((size_t)(h * 64 + row)) * ROWS + b * SS + kvt * 64 + chg * 8],
                            (char*)Vs + ldsoff + i * 4096);
            }
            __syncthreads();

            // S = Q K^T (Q pre-scaled by 1/8)
            f32x4 sc[4];
#pragma unroll
            for (int i = 0; i < 4; i++) sc[i] = (f32x4)0.f;
#pragma unroll
            for (int kk = 0; kk < 2; kk++) {
#pragma unroll
                for (int fn = 0; fn < 4; fn++) {
                    const int ch = (kk * 4 + l4) ^ (l15 & 7);
                    bf16x8 kb = *(const bf16x8*)&Ks[fn * 16 + l15][ch * 8];
                    sc[fn] = __builtin_amdgcn_mfma_f32_16x16x32_bf16(qa[kk], kb, sc[fn], 0, 0, 0);
                }
            }

            if (kvt == qt) {
#pragma unroll
                for (int fn = 0; fn < 4; fn++) {
                    const int kvg = fn * 16 + l15;
#pragma unroll
                    for (int r = 0; r < 4; r++) {
                        const int qg = wid * 16 + l4 * 4 + r;
                        if (kvg > qg) sc[fn][r] = -1e30f;
                    }
                }
            }

            float es[4], rs[4];
#pragma unroll
            for (int r = 0; r < 4; r++) {
                float v = fmaxf(fmaxf(sc[0][r], sc[1][r]), fmaxf(sc[2][r], sc[3][r]));
                v = fmaxf(v, __shfl_xor(v, 1));
                v = fmaxf(v, __shfl_xor(v, 2));
                v = fmaxf(v, __shfl_xor(v, 4));
                v = fmaxf(v, __shfl_xor(v, 8));
                const float mn = fmaxf(mrun[r], v);
                es[r] = __expf(mrun[r] - mn);
                mrun[r] = mn;
                rs[r] = 0.f;
            }
#pragma unroll
            for (int fn = 0; fn < 4; fn++)
#pragma unroll
                for (int r = 0; r < 4; r++) {
                    const float p = __expf(sc[fn][r] - mrun[r]);
                    sc[fn][r] = p;
                    rs[r] += p;
                }
#pragma unroll
            for (int r = 0; r < 4; r++) {
                float v = rs[r];
                v += __shfl_xor(v, 1);
                v += __shfl_xor(v, 2);
                v += __shfl_xor(v, 4);
                v += __shfl_xor(v, 8);
                lrun[r] = lrun[r] * es[r] + v;
            }
#pragma unroll
            for (int i = 0; i < 4; i++)
#pragma unroll
                for (int r = 0; r < 4; r++) accO[i][r] *= es[r];

#pragma unroll
            for (int fn = 0; fn < 4; fn++)
#pragma unroll
                for (int r = 0; r < 4; r++)
                    Ps[wid][l4 * 4 + r][fn * 16 + l15] = f2bf(sc[fn][r]);

#pragma unroll
            for (int kk = 0; kk < 2; kk++) {
                bf16x8 pa = *(const bf16x8*)&Ps[wid][l15][kk * 32 + l4 * 8];
#pragma unroll
                for (int fd = 0; fd < 4; fd++) {
                    const int ch = (kk * 4 + l4) ^ (l15 & 7);
                    bf16x8 vb = *(const bf16x8*)&Vs[fd * 16 + l15][ch * 8];
                    accO[fd] = __builtin_amdgcn_mfma_f32_16x16x32_bf16(pa, vb, accO[fd], 0, 0, 0);
                }
            }

            __syncthreads();
        }

        float inv[4];
#pragma unroll
        for (int r = 0; r < 4; r++) inv[r] = 1.0f / lrun[r];
#pragma unroll
        for (int fd = 0; fd < 4; fd++)
#pragma unroll
            for (int r = 0; r < 4; r++) {
                const int q = qt * 64 + wid * 16 + l4 * 4 + r;
                const size_t idx = ((size_t)b * SS + q) * DMODEL + h * 64 + fd * 16 + l15;
                Oc[idx] = f2bf(accO[fd][r] * inv[r]);
            }
    }
}

extern "C" void kernel_launch(void* const* d_in, const int* in_sizes, int n_in,
                              void* d_out, int out_size, void* d_ws, size_t ws_size,
                              hipStream_t stream) {
    const float* q   = (const float*)d_in[0];
    const float* k   = (const float*)d_in[1];
    const float* v   = (const float*)d_in[2];
    const float* w_q = (const float*)d_in[4];
    const float* b_q = (const float*)d_in[5];
    const float* w_k = (const float*)d_in[6];
    const float* b_k = (const float*)d_in[7];
    const float* w_v = (const float*)d_in[8];
    const float* b_v = (const float*)d_in[9];
    const float* w_o = (const float*)d_in[10];
    const float* b_o = (const float*)d_in[11];

    const size_t T = (size_t)ROWS * DMODEL;   // 4M elements
    short* Qh   = (short*)d_ws;               // [B,H,S,64] bf16
    short* Kh   = Qh + T;                     // [B,H,S,64] bf16
    short* Vt   = Kh + T;                     // [1024][4096] bf16 (V^T)
    short* VbOc = Vt + T;                     // Vb (pre-proj) then Oc (post-attn)
    short* Qb   = (short*)d_out;              // d_out as scratch: bf16 q
    short* Kb   = Qb + T;                     // bf16 k (d_out is 16MB = 2*T shorts)

    dim3 blk(256);
    // fp32 -> bf16: q,k -> d_out scratch, v -> ws (Oc slot)
    cvt3<<<dim3(1024, 3), blk, 0, stream>>>(q, k, v, Qb, Kb, VbOc);
    // Q projection (scaled 1/8), head-major
    gemm_bt<2, 1, 0, 0><<<dim3(8, 32), blk, 0, stream>>>(Qb, w_q, b_q, Qh, ROWS, DMODEL, 0.125f);
    // K projection, head-major
    gemm_bt<2, 1, 0, 0><<<dim3(8, 32), blk, 0, stream>>>(Kb, w_k, b_k, Kh, ROWS, DMODEL, 1.0f);
    // V projection transposed: Vt[e][bs] = sum_d w_v[e][d]*v_bf[bs][d] + b_v[e]
    gemm_bt<1, 0, 1, 1><<<dim3(32, 8), blk, 0, stream>>>(w_v, VbOc, b_v, Vt, DMODEL, ROWS, 1.0f);
    // attention (Vb dead -> Oc reuses its slot)
    attn_fwd<<<dim3(16, 32), blk, 0, stream>>>(Qh, Kh, Vt, VbOc);
    // output projection, fp32 out (overwrites Qb/Kb scratch, both dead)
    gemm_bt<0, 1, 0, 0><<<dim3(8, 32), blk, 0, stream>>>(VbOc, w_o, b_o, (float*)d_out, ROWS, DMODEL, 1.0f);
}

// Round 3
// 298.236 us; speedup vs baseline: 1.3891x; 1.2455x over previous
//
#include <hip/hip_runtime.h>
#include <hip/hip_bf16.h>

#define H 16
#define BB 2
#define SS 2048
#define DMODEL 1024
#define ROWS (BB * SS)   // 4096

typedef __attribute__((ext_vector_type(8))) short bf16x8;
typedef __attribute__((ext_vector_type(4))) float f32x4;

__device__ __forceinline__ short f2bf(float f) {
    union { float f; unsigned u; } v; v.f = f;
    unsigned r = v.u + 0x7fffu + ((v.u >> 16) & 1u);
    return (short)(r >> 16);
}

__device__ __forceinline__ void gload_lds16(const void* g, void* l) {
    __builtin_amdgcn_global_load_lds(
        (const __attribute__((address_space(1))) char*)g,
        (__attribute__((address_space(3))) char*)l, 16, 0, 0);
}

// fp32 -> bf16 convert for q,k,v. grid (1024, 3), 256 thr.
__global__ __launch_bounds__(256)
void cvt3(const float* __restrict__ q, const float* __restrict__ k,
          const float* __restrict__ v, short* __restrict__ dq,
          short* __restrict__ dk, short* __restrict__ dv)
{
    const float* s = (blockIdx.y == 0) ? q : (blockIdx.y == 1) ? k : v;
    short*       d = (blockIdx.y == 0) ? dq : (blockIdx.y == 1) ? dk : dv;
    const f32x4* sv = (const f32x4*)s;
    bf16x8* dv8 = (bf16x8*)d;
    int p = blockIdx.x * 256 + threadIdx.x;
#pragma unroll
    for (int it = 0; it < 2; ++it, p += 1024 * 256) {
        f32x4 a = sv[2 * p], c = sv[2 * p + 1];
        bf16x8 o;
        o[0] = f2bf(a[0]); o[1] = f2bf(a[1]); o[2] = f2bf(a[2]); o[3] = f2bf(a[3]);
        o[4] = f2bf(c[0]); o[5] = f2bf(c[1]); o[6] = f2bf(c[2]); o[7] = f2bf(c[3]);
        dv8[p] = o;
    }
}

// Stage a 128x32 fp32 tile (src pre-offset to tile origin, row stride ld)
// into bf16 LDS [128][32] linear. Thread t writes 16B chunks t and t+256
// -> lane-linear ds_write_b128, conflict-free.
__device__ __forceinline__ void stage_f32_128x32(const float* __restrict__ src,
                                                 size_t ld, short* dst, int t)
{
    const int r = t >> 2, c = (t & 3) * 8;
    {
        const f32x4* p = (const f32x4*)&src[(size_t)r * ld + c];
        f32x4 a = p[0], b = p[1];
        bf16x8 o;
        o[0]=f2bf(a[0]); o[1]=f2bf(a[1]); o[2]=f2bf(a[2]); o[3]=f2bf(a[3]);
        o[4]=f2bf(b[0]); o[5]=f2bf(b[1]); o[6]=f2bf(b[2]); o[7]=f2bf(b[3]);
        *(bf16x8*)((char*)dst + t * 16) = o;
    }
    {
        const f32x4* p = (const f32x4*)&src[(size_t)(r + 64) * ld + c];
        f32x4 a = p[0], b = p[1];
        bf16x8 o;
        o[0]=f2bf(a[0]); o[1]=f2bf(a[1]); o[2]=f2bf(a[2]); o[3]=f2bf(a[3]);
        o[4]=f2bf(b[0]); o[5]=f2bf(b[1]); o[6]=f2bf(b[2]); o[7]=f2bf(b[3]);
        *(bf16x8*)((char*)dst + 4096 + t * 16) = o;
    }
}

// Fused Q/K/V projection. Grid: 768 flat blocks, op = bid/256.
// op 0: Qh = (Qb @ w_q^T + b_q)*0.125, head-major [B,H,S,64]
// op 1: Kh = (Kb @ w_k^T + b_k),       head-major
// op 2: Vt = (w_v @ Vb^T + b_v),       row-major [1024][4096]
__global__ __launch_bounds__(256, 2)
void qkv_proj(const short* __restrict__ Qb, const short* __restrict__ Kb,
              const short* __restrict__ Vb,
              const float* __restrict__ wq, const float* __restrict__ bq,
              const float* __restrict__ wk, const float* __restrict__ bk,
              const float* __restrict__ wv, const float* __restrict__ bv,
              short* __restrict__ Qh, short* __restrict__ Kh,
              short* __restrict__ Vt)
{
    const int K = DMODEL;
    __shared__ short As[128 * 32];
    __shared__ short Bs[128 * 32];

    const int bid  = blockIdx.x;
    const int op   = bid >> 8;
    const int tile = bid & 255;
    const int t    = threadIdx.x;
    const int lane = t & 63;
    const int wid  = t >> 6;
    const int wm   = wid >> 1;
    const int wn   = wid & 1;
    const int l15  = lane & 15;
    const int l4   = lane >> 4;

    const short* Abf = nullptr; const float* Af = nullptr;
    const float* Bf  = nullptr; const short* Bbf = nullptr;
    const float* bias; short* C;
    int m0, n0; float scale = 1.0f; bool aBf;
    if (op == 0) {
        Abf = Qb; Bf = wq; bias = bq; C = Qh;
        m0 = (tile >> 3) * 128; n0 = (tile & 7) * 128; scale = 0.125f; aBf = true;
    } else if (op == 1) {
        Abf = Kb; Bf = wk; bias = bk; C = Kh;
        m0 = (tile >> 3) * 128; n0 = (tile & 7) * 128; aBf = true;
    } else {
        Af = wv; Bbf = Vb; bias = bv; C = Vt;
        m0 = (tile & 7) * 128; n0 = (tile >> 3) * 128; aBf = false;
    }

    f32x4 acc[4][4];
#pragma unroll
    for (int i = 0; i < 4; i++)
#pragma unroll
        for (int j = 0; j < 4; j++) acc[i][j] = (f32x4)0.0f;

    const int grow = wid * 16 + (lane >> 2);
    const int gcol = (lane & 3) * 8;

    for (int kt = 0; kt < K; kt += 32) {
        if (aBf) {
#pragma unroll
            for (int i = 0; i < 2; i++)
                gload_lds16(&Abf[(size_t)(m0 + i * 64 + grow) * K + kt + gcol],
                            (char*)As + wid * 1024 + i * 4096);
            stage_f32_128x32(Bf + (size_t)n0 * K + kt, K, Bs, t);
        } else {
            stage_f32_128x32(Af + (size_t)m0 * K + kt, K, As, t);
#pragma unroll
            for (int i = 0; i < 2; i++)
                gload_lds16(&Bbf[(size_t)(n0 + i * 64 + grow) * K + kt + gcol],
                            (char*)Bs + wid * 1024 + i * 4096);
        }
        __syncthreads();

        bf16x8 a[4], b[4];
#pragma unroll
        for (int i = 0; i < 4; i++)
            a[i] = *(const bf16x8*)&As[(wm * 64 + i * 16 + l15) * 32 + l4 * 8];
#pragma unroll
        for (int j = 0; j < 4; j++)
            b[j] = *(const bf16x8*)&Bs[(wn * 64 + j * 16 + l15) * 32 + l4 * 8];
#pragma unroll
        for (int i = 0; i < 4; i++)
#pragma unroll
            for (int j = 0; j < 4; j++)
                acc[i][j] = __builtin_amdgcn_mfma_f32_16x16x32_bf16(a[i], b[j], acc[i][j], 0, 0, 0);

        __syncthreads();
    }

#pragma unroll
    for (int i = 0; i < 4; i++) {
        const int mbase = m0 + wm * 64 + i * 16 + l4 * 4;
#pragma unroll
        for (int j = 0; j < 4; j++) {
            const int n = n0 + wn * 64 + j * 16 + l15;
#pragma unroll
            for (int r = 0; r < 4; r++) {
                const int m = mbase + r;
                if (op < 2) {
                    float y = (acc[i][j][r] + bias[n]) * scale;
                    const int b_ = m >> 11, s_ = m & 2047;
                    const int h_ = n >> 6,  d_ = n & 63;
                    C[((((size_t)b_ * H + h_) * SS + s_) << 6) + d_] = f2bf(y);
                } else {
                    C[(size_t)m * ROWS + n] = f2bf(acc[i][j][r] + bias[m]);
                }
            }
        }
    }
}

// O-projection: d_out[4096][1024] fp32 = Oc @ w_o^T + b_o. 64x128 tiles, 512 blocks.
__global__ __launch_bounds__(256, 2)
void oproj(const short* __restrict__ Oc, const float* __restrict__ wo,
           const float* __restrict__ bo, float* __restrict__ out)
{
    const int K = DMODEL;
    __shared__ short As[64 * 32];
    __shared__ short Bs[128 * 32];

    const int t    = threadIdx.x;
    const int lane = t & 63;
    const int wid  = t >> 6;
    const int wm   = wid >> 1;
    const int wn   = wid & 1;
    const int m0   = blockIdx.y * 64;
    const int n0   = blockIdx.x * 128;
    const int l15  = lane & 15;
    const int l4   = lane >> 4;

    f32x4 acc[2][4];
#pragma unroll
    for (int i = 0; i < 2; i++)
#pragma unroll
        for (int j = 0; j < 4; j++) acc[i][j] = (f32x4)0.0f;

    const int grow = wid * 16 + (lane >> 2);
    const int gcol = (lane & 3) * 8;

    for (int kt = 0; kt < K; kt += 32) {
        gload_lds16(&Oc[(size_t)(m0 + grow) * K + kt + gcol], (char*)As + wid * 1024);
        stage_f32_128x32(wo + (size_t)n0 * K + kt, K, Bs, t);
        __syncthreads();

        bf16x8 a[2], b[4];
#pragma unroll
        for (int i = 0; i < 2; i++)
            a[i] = *(const bf16x8*)&As[(wm * 32 + i * 16 + l15) * 32 + l4 * 8];
#pragma unroll
        for (int j = 0; j < 4; j++)
            b[j] = *(const bf16x8*)&Bs[(wn * 64 + j * 16 + l15) * 32 + l4 * 8];
#pragma unroll
        for (int i = 0; i < 2; i++)
#pragma unroll
            for (int j = 0; j < 4; j++)
                acc[i][j] = __builtin_amdgcn_mfma_f32_16x16x32_bf16(a[i], b[j], acc[i][j], 0, 0, 0);

        __syncthreads();
    }

#pragma unroll
    for (int i = 0; i < 2; i++) {
        const int mbase = m0 + wm * 32 + i * 16 + l4 * 4;
#pragma unroll
        for (int j = 0; j < 4; j++) {
            const int n = n0 + wn * 64 + j * 16 + l15;
#pragma unroll
            for (int r = 0; r < 4; r++)
                out[(size_t)(mbase + r) * DMODEL + n] = acc[i][j][r] + bo[n];
        }
    }
}

// Flash attention, causal, paired q-tiles, double-buffered K/V, 1 barrier/iter.
// Grid 512 flat; XCD-grouping swizzle puts the 16 same-bh blocks on one XCD.
__global__ __launch_bounds__(256, 2)
void attn_fwd(const short* __restrict__ Qh, const short* __restrict__ Kh,
              const short* __restrict__ Vt, short* __restrict__ Oc)
{
    __shared__ short Ks[2][64][64];
    __shared__ short Vs[2][64][64];
    __shared__ short Ps[4][16][72];

    const int t    = threadIdx.x;
    const int lane = t & 63;
    const int wid  = t >> 6;
    const int fbid = blockIdx.x;
    const int vbid = (fbid & 7) * 64 + (fbid >> 3);   // bijective; same-bh -> same XCD
    const int bh   = vbid >> 4;
    const int qp   = vbid & 15;
    const int b    = bh >> 4;
    const int h    = bh & 15;
    const int l15  = lane & 15;
    const int l4   = lane >> 4;

    const int srow = wid * 8 + (lane >> 3);
    const int sch  = lane & 7;
    const int ldsoff = wid * 1024;

    auto stage = [&](int buf, int kvt) {
#pragma unroll
        for (int i = 0; i < 2; i++) {
            const int row = i * 32 + srow;
            const int chg = sch ^ (row & 7);
            gload_lds16(&Kh[((size_t)bh * SS + kvt * 64 + row) * 64 + chg * 8],
                        (char*)Ks + buf * 8192 + ldsoff + i * 4096);
            gload_lds16(&Vt[((size_t)(h * 64 + row)) * ROWS + b * SS + kvt * 64 + chg * 8],
                        (char*)Vs + buf * 8192 + ldsoff + i * 4096);
        }
    };

    for (int half = 0; half < 2; ++half) {
        const int qt = half ? (31 - qp) : qp;

        bf16x8 qa[2];
        {
            const int qrow = qt * 64 + wid * 16 + l15;
            const size_t base = ((size_t)bh * SS + qrow) * 64;
            qa[0] = *(const bf16x8*)&Qh[base + l4 * 8];
            qa[1] = *(const bf16x8*)&Qh[base + 32 + l4 * 8];
        }

        f32x4 accO[4];
#pragma unroll
        for (int i = 0; i < 4; i++) accO[i] = (f32x4)0.f;
        float mrun[4], lrun[4];
#pragma unroll
        for (int r = 0; r < 4; r++) { mrun[r] = -1e30f; lrun[r] = 0.f; }

        stage(0, 0);
        __syncthreads();

        int cur = 0;
        for (int kvt = 0; kvt <= qt; ++kvt) {
            if (kvt < qt) stage(cur ^ 1, kvt + 1);   // prefetch overlaps compute

            f32x4 sc[4];
#pragma unroll
            for (int i = 0; i < 4; i++) sc[i] = (f32x4)0.f;
            __builtin_amdgcn_s_setprio(1);
#pragma unroll
            for (int kk = 0; kk < 2; kk++) {
#pragma unroll
                for (int fn = 0; fn < 4; fn++) {
                    const int ch = (kk * 4 + l4) ^ (l15 & 7);
                    bf16x8 kb = *(const bf16x8*)&Ks[cur][fn * 16 + l15][ch * 8];
                    sc[fn] = __builtin_amdgcn_mfma_f32_16x16x32_bf16(qa[kk], kb, sc[fn], 0, 0, 0);
                }
            }
            __builtin_amdgcn_s_setprio(0);

            if (kvt == qt) {
#pragma unroll
                for (int fn = 0; fn < 4; fn++) {
                    const int kvg = fn * 16 + l15;
#pragma unroll
                    for (int r = 0; r < 4; r++) {
                        const int qg = wid * 16 + l4 * 4 + r;
                        if (kvg > qg) sc[fn][r] = -1e30f;
                    }
                }
            }

            float es[4], rs[4];
#pragma unroll
            for (int r = 0; r < 4; r++) {
                float v = fmaxf(fmaxf(sc[0][r], sc[1][r]), fmaxf(sc[2][r], sc[3][r]));
                v = fmaxf(v, __shfl_xor(v, 1));
                v = fmaxf(v, __shfl_xor(v, 2));
                v = fmaxf(v, __shfl_xor(v, 4));
                v = fmaxf(v, __shfl_xor(v, 8));
                const float mn = fmaxf(mrun[r], v);
                es[r] = __expf(mrun[r] - mn);
                mrun[r] = mn;
                rs[r] = 0.f;
            }
#pragma unroll
            for (int fn = 0; fn < 4; fn++)
#pragma unroll
                for (int r = 0; r < 4; r++) {
                    const float p = __expf(sc[fn][r] - mrun[r]);
                    sc[fn][r] = p;
                    rs[r] += p;
                }
#pragma unroll
            for (int r = 0; r < 4; r++) {
                float v = rs[r];
                v += __shfl_xor(v, 1);
                v += __shfl_xor(v, 2);
                v += __shfl_xor(v, 4);
                v += __shfl_xor(v, 8);
                lrun[r] = lrun[r] * es[r] + v;
            }
#pragma unroll
            for (int i = 0; i < 4; i++)
#pragma unroll
                for (int r = 0; r < 4; r++) accO[i][r] *= es[r];

#pragma unroll
            for (int fn = 0; fn < 4; fn++)
#pragma unroll
                for (int r = 0; r < 4; r++)
                    Ps[wid][l4 * 4 + r][fn * 16 + l15] = f2bf(sc[fn][r]);

            __builtin_amdgcn_s_setprio(1);
#pragma unroll
            for (int kk = 0; kk < 2; kk++) {
                bf16x8 pa = *(const bf16x8*)&Ps[wid][l15][kk * 32 + l4 * 8];
#pragma unroll
                for (int fd = 0; fd < 4; fd++) {
                    const int ch = (kk * 4 + l4) ^ (l15 & 7);
                    bf16x8 vb = *(const bf16x8*)&Vs[cur][fd * 16 + l15][ch * 8];
                    accO[fd] = __builtin_amdgcn_mfma_f32_16x16x32_bf16(pa, vb, accO[fd], 0, 0, 0);
                }
            }
            __builtin_amdgcn_s_setprio(0);

            __syncthreads();   // drains prefetch vmcnt + protects both buffers
            cur ^= 1;
        }

        float inv[4];
#pragma unroll
        for (int r = 0; r < 4; r++) inv[r] = 1.0f / lrun[r];
#pragma unroll
        for (int fd = 0; fd < 4; fd++)
#pragma unroll
            for (int r = 0; r < 4; r++) {
                const int q = qt * 64 + wid * 16 + l4 * 4 + r;
                const size_t idx = ((size_t)b * SS + q) * DMODEL + h * 64 + fd * 16 + l15;
                Oc[idx] = f2bf(accO[fd][r] * inv[r]);
            }
    }
}

extern "C" void kernel_launch(void* const* d_in, const int* in_sizes, int n_in,
                              void* d_out, int out_size, void* d_ws, size_t ws_size,
                              hipStream_t stream) {
    const float* q   = (const float*)d_in[0];
    const float* k   = (const float*)d_in[1];
    const float* v   = (const float*)d_in[2];
    const float* w_q = (const float*)d_in[4];
    const float* b_q = (const float*)d_in[5];
    const float* w_k = (const float*)d_in[6];
    const float* b_k = (const float*)d_in[7];
    const float* w_v = (const float*)d_in[8];
    const float* b_v = (const float*)d_in[9];
    const float* w_o = (const float*)d_in[10];
    const float* b_o = (const float*)d_in[11];

    const size_t T = (size_t)ROWS * DMODEL;   // 4M elements
    short* Qh   = (short*)d_ws;               // [B,H,S,64] bf16
    short* Kh   = Qh + T;                     // [B,H,S,64] bf16
    short* Vt   = Kh + T;                     // [1024][4096] bf16 (V^T)
    short* VbOc = Vt + T;                     // Vb (pre-proj) then Oc (post-attn)
    short* Qb   = (short*)d_out;              // d_out as scratch: bf16 q
    short* Kb   = Qb + T;                     // bf16 k

    dim3 blk(256);
    cvt3<<<dim3(1024, 3), blk, 0, stream>>>(q, k, v, Qb, Kb, VbOc);
    qkv_proj<<<dim3(768), blk, 0, stream>>>(Qb, Kb, VbOc,
                                            w_q, b_q, w_k, b_k, w_v, b_v,
                                            Qh, Kh, Vt);
    attn_fwd<<<dim3(512), blk, 0, stream>>>(Qh, Kh, Vt, VbOc);
    oproj<<<dim3(8, 64), blk, 0, stream>>>(VbOc, w_o, b_o, (float*)d_out);
}